// Round 8
// baseline (237.958 us; speedup 1.0000x reference)
//
#include <hip/hip_runtime.h>

// ---------------------------------------------------------------------------
// MultiHeadAttention graph-attention kernel for MI355X (gfx950).  Round 8.
// R7 with the nontemporal-store compile fix (ext_vector f32x4, not float4).
// GEMM: m201-style 256x256 tile, BK=64, 8 waves (2Mx4N, wave tile 128x64),
// double-buffered 128KB LDS, 4 phases/K-tile (16 MFMA each), stage-all-at-P0
// with counted vmcnt(8), per-phase barrier pairs, setprio, XOR LDS swizzle.
// Rest of pipeline as R6 (Wc=Wo@Wv folding, packed CSR pairs, node_msg).
// ---------------------------------------------------------------------------

#define C_DIM 512
#define TEMP_INV (1.0f / 22.627416997969522f)   // 1/sqrt(512)

using bf16x8 = __attribute__((ext_vector_type(8))) __bf16;
using s16x8  = __attribute__((ext_vector_type(8))) short;
using s16x4  = __attribute__((ext_vector_type(4))) short;
using f32x4  = __attribute__((ext_vector_type(4))) float;

__device__ __forceinline__ float bf2f(short u) {
    union { unsigned u; float f; } t;
    t.u = ((unsigned)(unsigned short)u) << 16;
    return t.f;
}
__device__ __forceinline__ short f2bf(float f) {
    union { float f; unsigned u; } t;
    t.f = f;
    unsigned r = t.u + 0x7FFFu + ((t.u >> 16) & 1u);  // RNE
    return (short)(r >> 16);
}

// ------------------- fp32 -> bf16 converts ---------------------------------
__global__ void cvt2_f32_bf16(const float* __restrict__ inA,
                              const float* __restrict__ inB,
                              short* __restrict__ out, long n4half) {
    long i = (long)blockIdx.x * blockDim.x + threadIdx.x;
    long stride = (long)gridDim.x * blockDim.x;
    long n4 = 2 * n4half;
    for (; i < n4; i += stride) {
        const float4* src = (i < n4half)
            ? reinterpret_cast<const float4*>(inA) + i
            : reinterpret_cast<const float4*>(inB) + (i - n4half);
        float4 v = *src;
        s16x4 o;
        o[0] = f2bf(v.x); o[1] = f2bf(v.y); o[2] = f2bf(v.z); o[3] = f2bf(v.w);
        reinterpret_cast<s16x4*>(out)[i] = o;
    }
}

// blocks 0-63: WvT transpose-convert; 64-127: Wk -> Wkc rows 0-511;
// 128-191: Wo -> WoB.
__global__ void cvt_weights(const float* __restrict__ Wk,
                            const float* __restrict__ Wv,
                            const float* __restrict__ Wo,
                            short* __restrict__ Wkc, short* __restrict__ WoB,
                            short* __restrict__ WvT) {
    int b = blockIdx.x;
    int tid = threadIdx.x;
    if (b < 64) {
        __shared__ float t[64][65];
        int bx = b & 7, by = b >> 3;
#pragma unroll
        for (int i = 0; i < 4; ++i) {
            int idx = i * 256 + tid;
            int row = idx >> 4, c4 = idx & 15;
            float4 v = *(const float4*)&Wv[(size_t)(by * 64 + row) * 512 + bx * 64 + c4 * 4];
            t[row][c4 * 4 + 0] = v.x; t[row][c4 * 4 + 1] = v.y;
            t[row][c4 * 4 + 2] = v.z; t[row][c4 * 4 + 3] = v.w;
        }
        __syncthreads();
#pragma unroll
        for (int i = 0; i < 4; ++i) {
            int idx = i * 256 + tid;
            int row = idx >> 4, g = idx & 15;
            s16x4 o;
            o[0] = f2bf(t[g * 4 + 0][row]);
            o[1] = f2bf(t[g * 4 + 1][row]);
            o[2] = f2bf(t[g * 4 + 2][row]);
            o[3] = f2bf(t[g * 4 + 3][row]);
            *(s16x4*)&WvT[(size_t)(bx * 64 + row) * 512 + by * 64 + g * 4] = o;
        }
    } else {
        const float* src = (b < 128) ? Wk : Wo;
        short* dst = (b < 128) ? Wkc : WoB;
        long base = (long)(b & 63) * 1024;   // float4 units
#pragma unroll
        for (int i = 0; i < 4; ++i) {
            long idx = base + i * 256 + tid;
            float4 v = reinterpret_cast<const float4*>(src)[idx];
            s16x4 o;
            o[0] = f2bf(v.x); o[1] = f2bf(v.y); o[2] = f2bf(v.z); o[3] = f2bf(v.w);
            reinterpret_cast<s16x4*>(dst)[idx] = o;
        }
    }
}

// ------------------------------- bf16 GEMM ---------------------------------
// C[M,N] = A[M,K] @ B[N,K]^T, bf16 out.  256x256 tile, BK=64, 8 waves
// (2M x 4N), wave tile 128x64.  Double-buffered 128KB LDS.
// Half-tile = [128 rows][64 bf16 cols] (128B rows, 8 granules of 16B);
// granule g of row r stored at slot g ^ (r&7)  (involution; 0 conflicts
// measured in R4/R6).  Per K-tile: stage all 4 next halves at P0 + vmcnt(8),
// then 4 phases of {ds_read quadrant, lgkm(0), 16 MFMA, barrier}.

// stage one half-tile (128 x 64 bf16) rows [row0,row0+128) cols [k0,k0+64)
__device__ __forceinline__ void stage_half(const short* __restrict__ mat,
                                           int row0, int k0, int K, int M,
                                           short* dst, int tid) {
#pragma unroll
    for (int j = 0; j < 2; ++j) {
        int L    = j * 512 + tid;            // linear LDS granule 0..1023
        int pr   = L >> 3;                   // row 0..127
        int slot = L & 7;
        int g    = slot ^ (pr & 7);          // logical granule (inverse swz)
        int gr   = row0 + pr; if (gr >= M) gr = M - 1;
        const short* s = mat + (size_t)gr * K + k0 + g * 8;
        int wb = (j * 512 + (tid & ~63)) * 16;   // wave-uniform base (bytes)
        __builtin_amdgcn_global_load_lds(
            (__attribute__((address_space(1))) void*)s,
            (__attribute__((address_space(3))) void*)((char*)dst + wb),
            16, 0, 0);
    }
}

__global__ __launch_bounds__(512, 2)
void gemm256(const short* __restrict__ A, const short* __restrict__ B,
             short* __restrict__ Cp, int M, int N, int K, int nn, int total) {
    __shared__ short As[2][2][128 * 64];   // [buf][half][row][col]  64KB
    __shared__ short Bs[2][2][128 * 64];   //                        64KB

    // bijective XCD-chunked block swizzle (m204)
    const int bid = blockIdx.x;
    const int q = total >> 3, r = total & 7;
    const int xcd = bid & 7, idx = bid >> 3;
    const int swz = (xcd < r ? xcd * (q + 1) : r * (q + 1) + (xcd - r) * q) + idx;
    const int bm = (swz / nn) * 256;
    const int bn = (swz % nn) * 256;

    const int tid   = threadIdx.x;
    const int lane  = tid & 63;
    const int wid   = tid >> 6;      // 0..7
    const int wm    = wid >> 2;      // 0..1: A-half, rows wm*128
    const int wn    = wid & 3;       // 0..3: cols wn*64; B-half = wn>>1
    const int lrow  = lane & 15;
    const int khalf = lane >> 4;     // 0..3
    const int brow0 = (wn & 1) * 64;

    f32x4 acc[8][4] = {};
    bf16x8 a[4][2], b[4][2];

    const int nt = K >> 6;   // K-tiles of 64

    // prologue: stage K-tile 0 (4 halves, 8 loads/thread)
    stage_half(A, bm,       0, K, M, As[0][0], tid);
    stage_half(A, bm + 128, 0, K, M, As[0][1], tid);
    stage_half(B, bn,       0, K, N, Bs[0][0], tid);
    stage_half(B, bn + 128, 0, K, N, Bs[0][1], tid);

    for (int kt = 0; kt < nt; ++kt) {
        const int buf = kt & 1;
        const short* Ah = As[buf][wm];
        const short* Bh = Bs[buf][wn >> 1];
        const bool pre = (kt + 1) < nt;
        const int k1 = (kt + 1) << 6;

        auto frag = [&](const short* h, int row, int ks) -> bf16x8 {
            int g = ks * 4 + khalf;
            int slot = g ^ (row & 7);
            return *(const bf16x8*)&h[row * 64 + slot * 8];
        };

        // ---- P0: stage ALL next halves, counted vmcnt, quadrant (lo,lo) ----
        if (pre) {
            stage_half(A, bm,       k1, K, M, As[buf ^ 1][0], tid);
            stage_half(A, bm + 128, k1, K, M, As[buf ^ 1][1], tid);
            stage_half(B, bn,       k1, K, N, Bs[buf ^ 1][0], tid);
            stage_half(B, bn + 128, k1, K, N, Bs[buf ^ 1][1], tid);
            asm volatile("s_waitcnt vmcnt(8)" ::: "memory");  // tile kt landed
        } else {
            asm volatile("s_waitcnt vmcnt(0)" ::: "memory");
        }
        __builtin_amdgcn_s_barrier();   // buf[kt] ready for all waves

#pragma unroll
        for (int mf = 0; mf < 4; ++mf)
#pragma unroll
            for (int ks = 0; ks < 2; ++ks)
                a[mf][ks] = frag(Ah, mf * 16 + lrow, ks);
#pragma unroll
        for (int nf = 0; nf < 2; ++nf)
#pragma unroll
            for (int ks = 0; ks < 2; ++ks)
                b[nf][ks] = frag(Bh, brow0 + nf * 16 + lrow, ks);
        asm volatile("s_waitcnt lgkmcnt(0)" ::: "memory");
        __builtin_amdgcn_sched_barrier(0);
        __builtin_amdgcn_s_setprio(1);
#pragma unroll
        for (int mf = 0; mf < 4; ++mf)
#pragma unroll
            for (int nf = 0; nf < 2; ++nf)
#pragma unroll
                for (int ks = 0; ks < 2; ++ks)
                    acc[mf][nf] = __builtin_amdgcn_mfma_f32_16x16x32_bf16(
                        a[mf][ks], b[nf][ks], acc[mf][nf], 0, 0, 0);
        __builtin_amdgcn_s_setprio(0);
        __builtin_amdgcn_s_barrier();

        // ---- P1: quadrant (lo, hi) -- read b2-3 ----
#pragma unroll
        for (int nf = 2; nf < 4; ++nf)
#pragma unroll
            for (int ks = 0; ks < 2; ++ks)
                b[nf][ks] = frag(Bh, brow0 + nf * 16 + lrow, ks);
        asm volatile("s_waitcnt lgkmcnt(0)" ::: "memory");
        __builtin_amdgcn_sched_barrier(0);
        __builtin_amdgcn_s_setprio(1);
#pragma unroll
        for (int mf = 0; mf < 4; ++mf)
#pragma unroll
            for (int nf = 2; nf < 4; ++nf)
#pragma unroll
                for (int ks = 0; ks < 2; ++ks)
                    acc[mf][nf] = __builtin_amdgcn_mfma_f32_16x16x32_bf16(
                        a[mf][ks], b[nf][ks], acc[mf][nf], 0, 0, 0);
        __builtin_amdgcn_s_setprio(0);
        __builtin_amdgcn_s_barrier();

        // ---- P2: quadrant (hi, lo) -- read a4-7 (reuse a[] regs) ----
#pragma unroll
        for (int mf = 0; mf < 4; ++mf)
#pragma unroll
            for (int ks = 0; ks < 2; ++ks)
                a[mf][ks] = frag(Ah, 64 + mf * 16 + lrow, ks);
        asm volatile("s_waitcnt lgkmcnt(0)" ::: "memory");
        __builtin_amdgcn_sched_barrier(0);
        __builtin_amdgcn_s_setprio(1);
#pragma unroll
        for (int mf = 0; mf < 4; ++mf)
#pragma unroll
            for (int nf = 0; nf < 2; ++nf)
#pragma unroll
                for (int ks = 0; ks < 2; ++ks)
                    acc[4 + mf][nf] = __builtin_amdgcn_mfma_f32_16x16x32_bf16(
                        a[mf][ks], b[nf][ks], acc[4 + mf][nf], 0, 0, 0);
        __builtin_amdgcn_s_setprio(0);
        __builtin_amdgcn_s_barrier();

        // ---- P3: quadrant (hi, hi) -- all operands live ----
        __builtin_amdgcn_s_setprio(1);
#pragma unroll
        for (int mf = 0; mf < 4; ++mf)
#pragma unroll
            for (int nf = 2; nf < 4; ++nf)
#pragma unroll
                for (int ks = 0; ks < 2; ++ks)
                    acc[4 + mf][nf] = __builtin_amdgcn_mfma_f32_16x16x32_bf16(
                        a[mf][ks], b[nf][ks], acc[4 + mf][nf], 0, 0, 0);
        __builtin_amdgcn_s_setprio(0);
        __builtin_amdgcn_s_barrier();
    }

    // ---- epilogue: D mapping col=lane&15, row=(lane>>4)*4+r  [m89] ----
    const int crow0 = (lane >> 4) * 4;
    const int ccol  = lane & 15;
#pragma unroll
    for (int qf = 0; qf < 8; ++qf) {
#pragma unroll
        for (int nf = 0; nf < 4; ++nf) {
            int col = bn + wn * 64 + nf * 16 + ccol;
#pragma unroll
            for (int r2 = 0; r2 < 4; ++r2) {
                int row = bm + wm * 128 + qf * 16 + crow0 + r2;
                if (row < M) Cp[(size_t)row * N + col] = f2bf(acc[qf][nf][r2]);
            }
        }
    }
}

// ---------------- per-edge unnormalized weight + degree count ---------------
__global__ void edge_dot(const short* __restrict__ proj,
                         const int* __restrict__ segL, const int* __restrict__ segR,
                         float* __restrict__ w, int* __restrict__ cnt,
                         int E, int N) {
    int e0 = blockIdx.x * 16 + (threadIdx.x >> 6) * 4;
    if (e0 >= E) return;
    int lane = threadIdx.x & 63;

    int e[4];
    float sum[4];
#pragma unroll
    for (int k = 0; k < 4; ++k) {
        int ek = e0 + k;
        e[k] = (ek < E) ? ek : e0;
        const short* a = proj + (size_t)segL[e[k]] * 1024 + lane * 8;          // K_L
        const short* b = proj + (size_t)(N + segR[e[k]]) * 1024 + lane * 8;    // K_R
        s16x8 va = *(const s16x8*)a;
        s16x8 vb = *(const s16x8*)b;
        float s = 0.f;
#pragma unroll
        for (int j = 0; j < 8; ++j) s += bf2f(va[j]) * bf2f(vb[j]);
        sum[k] = s;
    }
#pragma unroll
    for (int o = 32; o > 0; o >>= 1) {
#pragma unroll
        for (int k = 0; k < 4; ++k) sum[k] += __shfl_xor(sum[k], o, 64);
    }
    if (lane < 4) {
        int ek = e0 + lane;
        if (ek < E) {
            float s = (lane == 0) ? sum[0] : (lane == 1) ? sum[1]
                    : (lane == 2) ? sum[2] : sum[3];
            w[ek] = __expf(s * TEMP_INV);
            atomicAdd(&cnt[segL[ek]], 1);
            atomicAdd(&cnt[N + segR[ek]], 1);
        }
    }
}

// ------------------------------- CSR scan ----------------------------------
__global__ void scan_blocks(const int* __restrict__ cnt, int* __restrict__ off,
                            int* __restrict__ bsum, int n) {
    __shared__ int ws[4];
    int tid = threadIdx.x, lane = tid & 63, wid = tid >> 6;
    int i = blockIdx.x * 256 + tid;
    int x = (i < n) ? cnt[i] : 0;
    int v = x;
#pragma unroll
    for (int d = 1; d < 64; d <<= 1) {
        int t = __shfl_up(v, d, 64);
        if (lane >= d) v += t;
    }
    if (lane == 63) ws[wid] = v;
    __syncthreads();
    int woff = 0;
    for (int w = 0; w < wid; ++w) woff += ws[w];
    v += woff;
    if (i < n) off[i + 1] = v;
    if (tid == 255) bsum[blockIdx.x] = v;
}

__global__ void scan_tops(int* __restrict__ bsum, int nb) {
    __shared__ int ws[4];
    int tid = threadIdx.x, lane = tid & 63, wid = tid >> 6;
    int x = (tid < nb) ? bsum[tid] : 0;
    int v = x;
#pragma unroll
    for (int d = 1; d < 64; d <<= 1) {
        int t = __shfl_up(v, d, 64);
        if (lane >= d) v += t;
    }
    if (lane == 63) ws[wid] = v;
    __syncthreads();
    int woff = 0;
    for (int w = 0; w < wid; ++w) woff += ws[w];
    v += woff;
    if (tid < nb) bsum[tid] = v - x;
}

__global__ void scan_apply(int* __restrict__ off, const int* __restrict__ bsum,
                           int* __restrict__ cnt, int n) {
    int i = blockIdx.x * 256 + threadIdx.x;
    if (i < n) {
        off[i + 1] += bsum[blockIdx.x];
        cnt[i] = 0;
    }
    if (i == 0) off[0] = 0;
}

// fill packed (w, abs_src_row) pairs into CSR slots
__global__ void fill_csr2(const int* __restrict__ segL, const int* __restrict__ segR,
                          const float* __restrict__ w,
                          const int* __restrict__ off, int* __restrict__ cur,
                          float2* __restrict__ pairs, int E, int N) {
    int i = blockIdx.x * blockDim.x + threadIdx.x;
    int st = gridDim.x * blockDim.x;
    for (; i < E; i += st) {
        int sl = segL[i], sr = segR[i];
        float we = w[i];
        int pl = off[sl] + atomicAdd(&cur[sl], 1);
        pairs[pl] = make_float2(we, __int_as_float(N + sr));   // left dest <- R src
        int pr = off[N + sr] + atomicAdd(&cur[N + sr], 1);
        pairs[pr] = make_float2(we, __int_as_float(sl));       // right dest <- L src
    }
}

// --------- per-node weighted VW sum + normalize + bias + LeakyReLU ----------
__global__ void node_msg(const int* __restrict__ off,
                         const float2* __restrict__ pairs,
                         const short* __restrict__ proj,
                         const float* __restrict__ bo,
                         float* __restrict__ out, int NN2) {
    int n = blockIdx.x * 4 + (threadIdx.x >> 6);
    if (n >= NN2) return;
    int lane = threadIdx.x & 63;
    int beg = off[n], end = off[n + 1];
    const short* VW = proj + 512 + lane * 8;   // VW half, stride 1024

    float acc[8] = {};
    float z = 0.f;
    int i = beg;
    for (; i + 3 < end; i += 4) {
        float2 p0 = pairs[i], p1 = pairs[i + 1];
        float2 p2 = pairs[i + 2], p3 = pairs[i + 3];
        const s16x8 v0 = *(const s16x8*)(VW + (size_t)__float_as_int(p0.y) * 1024);
        const s16x8 v1 = *(const s16x8*)(VW + (size_t)__float_as_int(p1.y) * 1024);
        const s16x8 v2 = *(const s16x8*)(VW + (size_t)__float_as_int(p2.y) * 1024);
        const s16x8 v3 = *(const s16x8*)(VW + (size_t)__float_as_int(p3.y) * 1024);
        z += (p0.x + p1.x) + (p2.x + p3.x);
#pragma unroll
        for (int j = 0; j < 8; ++j) {
            acc[j] += p0.x * bf2f(v0[j]) + p1.x * bf2f(v1[j]);
            acc[j] += p2.x * bf2f(v2[j]) + p3.x * bf2f(v3[j]);
        }
    }
    for (; i < end; ++i) {
        float2 p = pairs[i];
        const s16x8 v = *(const s16x8*)(VW + (size_t)__float_as_int(p.y) * 1024);
        z += p.x;
#pragma unroll
        for (int j = 0; j < 8; ++j) acc[j] += p.x * bf2f(v[j]);
    }
    float inv = (z > 0.f) ? 1.f / z : 0.f;

    float4 bs0 = *(const float4*)&bo[lane * 8];
    float4 bs1 = *(const float4*)&bo[lane * 8 + 4];
    float bb[8] = {bs0.x, bs0.y, bs0.z, bs0.w, bs1.x, bs1.y, bs1.z, bs1.w};
    f32x4 h0, h1;
#pragma unroll
    for (int j = 0; j < 4; ++j) {
        float v = acc[j] * inv + bb[j];
        h0[j] = v >= 0.f ? v : 0.01f * v;   // LeakyReLU
    }
#pragma unroll
    for (int j = 0; j < 4; ++j) {
        float v = acc[4 + j] * inv + bb[4 + j];
        h1[j] = v >= 0.f ? v : 0.01f * v;
    }
    float* orow = out + (size_t)n * C_DIM + lane * 8;
    __builtin_nontemporal_store(h0, (f32x4*)&orow[0]);
    __builtin_nontemporal_store(h1, (f32x4*)&orow[4]);
}

// ------------------------------- launcher ----------------------------------
extern "C" void kernel_launch(void* const* d_in, const int* in_sizes, int n_in,
                              void* d_out, int out_size, void* d_ws, size_t ws_size,
                              hipStream_t stream) {
    const float* node_left  = (const float*)d_in[0];
    const int*   segL       = (const int*)d_in[1];
    const float* node_right = (const float*)d_in[3];
    const int*   segR       = (const int*)d_in[4];
    const float* Wk         = (const float*)d_in[6];
    const float* Wv         = (const float*)d_in[7];
    const float* Wo         = (const float*)d_in[8];
    const float* bo         = (const float*)d_in[9];

    const int C = C_DIM;
    const int N = in_sizes[0] / C;   // 20000
    const int E = in_sizes[1];       // 160000
    const int NN2 = 2 * N;

    size_t offb = 0;
    auto alloc = [&](size_t bytes) -> void* {
        void* p = (char*)d_ws + offb;
        offb += (bytes + 255) & ~(size_t)255;
        return p;
    };
    short* nodeLR_b = (short*)alloc((size_t)NN2 * C * 2);     // [2N][512]
    short* Wkc_b  = (short*)alloc((size_t)1024 * C * 2);      // [Wk; Wc]
    short* Wc_b   = Wkc_b + (size_t)C * C;                    // rows 512-1023
    short* Wo_b   = (short*)alloc((size_t)C * C * 2);
    short* WvT_b  = (short*)alloc((size_t)C * C * 2);
    short* proj   = (short*)alloc((size_t)NN2 * 1024 * 2);    // [2N][1024] = [K|VW]
    float* w_arr  = (float*)alloc((size_t)E * 4);
    float2* pairs = (float2*)alloc((size_t)2 * E * 8);
    int* cnt  = (int*)alloc((size_t)NN2 * 4);
    int* off  = (int*)alloc((size_t)(NN2 + 1) * 4);
    int* bsum = (int*)alloc(256 * 4);

    const int nsb = (NN2 + 255) / 256;

    // 1. converts (cnt zeroing overlapped here, needed before edge_dot)
    hipMemsetAsync(cnt, 0, (size_t)NN2 * 4, stream);
    cvt2_f32_bf16<<<2048, 256, 0, stream>>>(node_left, node_right, nodeLR_b,
                                            (long)N * C / 4);
    cvt_weights<<<192, 256, 0, stream>>>(Wk, Wv, Wo, Wkc_b, Wo_b, WvT_b);

    // 2. Wc = Wo @ Wv;  proj = nodeLR @ [Wk; Wc]^T
    gemm256<<<4, 512, 0, stream>>>(Wo_b, WvT_b, Wc_b, C, C, C, 2, 4);
    {
        int nm = (NN2 + 255) / 256, nn = 1024 / 256;
        int total = nm * nn;
        gemm256<<<total, 512, 0, stream>>>(nodeLR_b, Wkc_b, proj, NN2, 1024, C,
                                           nn, total);
    }

    // 3. edge weights (unnormalized exp) + degree counts
    edge_dot<<<(E + 15) / 16, 256, 0, stream>>>(proj, segL, segR, w_arr, cnt, E, N);

    // 4. CSR scan + fill packed pairs
    scan_blocks<<<nsb, 256, 0, stream>>>(cnt, off, bsum, NN2);
    scan_tops<<<1, 256, 0, stream>>>(bsum, nsb);
    scan_apply<<<nsb, 256, 0, stream>>>(off, bsum, cnt, NN2);
    fill_csr2<<<512, 256, 0, stream>>>(segL, segR, w_arr, off, cnt, pairs, E, N);

    // 5. per-node weighted VW accumulate + bias + LeakyReLU -> d_out
    node_msg<<<(NN2 + 3) / 4, 256, 0, stream>>>(off, pairs, proj, bo,
                                                (float*)d_out, NN2);
}

// Round 9
// 230.129 us; speedup vs baseline: 1.0340x; 1.0340x over previous
//
#include <hip/hip_runtime.h>

// ---------------------------------------------------------------------------
// MultiHeadAttention graph-attention kernel for MI355X (gfx950).  Round 9.
// - GEMM: back to proven 128x128/BK=32 (R6) but with 3-buffer deep pipeline
//   (stage t+2 at iter t, steady-state vmcnt(8)) -- covers L2/HBM latency.
// - CSR restructured: count_edges + scans run BEFORE the GEMMs; edge_dot
//   computes w and writes packed (w, src_row) pairs directly (fill fused).
// - node_msg unchanged (packed pairs, 2-deep chain, nontemporal stores).
// ---------------------------------------------------------------------------

#define C_DIM 512
#define TEMP_INV (1.0f / 22.627416997969522f)   // 1/sqrt(512)

using bf16x8 = __attribute__((ext_vector_type(8))) __bf16;
using s16x8  = __attribute__((ext_vector_type(8))) short;
using s16x4  = __attribute__((ext_vector_type(4))) short;
using f32x4  = __attribute__((ext_vector_type(4))) float;

__device__ __forceinline__ float bf2f(short u) {
    union { unsigned u; float f; } t;
    t.u = ((unsigned)(unsigned short)u) << 16;
    return t.f;
}
__device__ __forceinline__ short f2bf(float f) {
    union { float f; unsigned u; } t;
    t.f = f;
    unsigned r = t.u + 0x7FFFu + ((t.u >> 16) & 1u);  // RNE
    return (short)(r >> 16);
}

// ------------------- fp32 -> bf16 converts ---------------------------------
__global__ void cvt2_f32_bf16(const float* __restrict__ inA,
                              const float* __restrict__ inB,
                              short* __restrict__ out, long n4half) {
    long i = (long)blockIdx.x * blockDim.x + threadIdx.x;
    long stride = (long)gridDim.x * blockDim.x;
    long n4 = 2 * n4half;
    for (; i < n4; i += stride) {
        const float4* src = (i < n4half)
            ? reinterpret_cast<const float4*>(inA) + i
            : reinterpret_cast<const float4*>(inB) + (i - n4half);
        float4 v = *src;
        s16x4 o;
        o[0] = f2bf(v.x); o[1] = f2bf(v.y); o[2] = f2bf(v.z); o[3] = f2bf(v.w);
        reinterpret_cast<s16x4*>(out)[i] = o;
    }
}

// blocks 0-63: WvT transpose-convert; 64-127: Wk -> Wkc rows 0-511;
// 128-191: Wo -> WoB.
__global__ void cvt_weights(const float* __restrict__ Wk,
                            const float* __restrict__ Wv,
                            const float* __restrict__ Wo,
                            short* __restrict__ Wkc, short* __restrict__ WoB,
                            short* __restrict__ WvT) {
    int b = blockIdx.x;
    int tid = threadIdx.x;
    if (b < 64) {
        __shared__ float t[64][65];
        int bx = b & 7, by = b >> 3;
#pragma unroll
        for (int i = 0; i < 4; ++i) {
            int idx = i * 256 + tid;
            int row = idx >> 4, c4 = idx & 15;
            float4 v = *(const float4*)&Wv[(size_t)(by * 64 + row) * 512 + bx * 64 + c4 * 4];
            t[row][c4 * 4 + 0] = v.x; t[row][c4 * 4 + 1] = v.y;
            t[row][c4 * 4 + 2] = v.z; t[row][c4 * 4 + 3] = v.w;
        }
        __syncthreads();
#pragma unroll
        for (int i = 0; i < 4; ++i) {
            int idx = i * 256 + tid;
            int row = idx >> 4, g = idx & 15;
            s16x4 o;
            o[0] = f2bf(t[g * 4 + 0][row]);
            o[1] = f2bf(t[g * 4 + 1][row]);
            o[2] = f2bf(t[g * 4 + 2][row]);
            o[3] = f2bf(t[g * 4 + 3][row]);
            *(s16x4*)&WvT[(size_t)(bx * 64 + row) * 512 + by * 64 + g * 4] = o;
        }
    } else {
        const float* src = (b < 128) ? Wk : Wo;
        short* dst = (b < 128) ? Wkc : WoB;
        long base = (long)(b & 63) * 1024;   // float4 units
#pragma unroll
        for (int i = 0; i < 4; ++i) {
            long idx = base + i * 256 + tid;
            float4 v = reinterpret_cast<const float4*>(src)[idx];
            s16x4 o;
            o[0] = f2bf(v.x); o[1] = f2bf(v.y); o[2] = f2bf(v.z); o[3] = f2bf(v.w);
            reinterpret_cast<s16x4*>(dst)[idx] = o;
        }
    }
}

// ------------------------------- bf16 GEMM ---------------------------------
// C[M,N] = A[M,K] @ B[N,K]^T, bf16 out.  128x128 tile, BK=32, 4 waves (2x2),
// 3-buffer deep pipeline (stage t+2 at iter t; steady-state vmcnt(8)),
// XCD-chunked block swizzle, paired-row zero-conflict LDS layout.
__global__ __launch_bounds__(256, 3)
void gemm_bt(const short* __restrict__ A, const short* __restrict__ B,
             short* __restrict__ Cp, int M, int N, int K, int nn, int total) {
    __shared__ short As[3][128 * 32];   // 24KB
    __shared__ short Bs[3][128 * 32];   // 24KB

    // bijective XCD-chunked block swizzle (m204)
    const int bid = blockIdx.x;
    const int q = total >> 3, r = total & 7;
    const int xcd = bid & 7, idx = bid >> 3;
    const int swz = (xcd < r ? xcd * (q + 1) : r * (q + 1) + (xcd - r) * q) + idx;
    const int bm = (swz / nn) * 128;
    const int bn = (swz % nn) * 128;

    const int tid  = threadIdx.x;
    const int lane = tid & 63;
    const int wid  = tid >> 6;
    const int wm   = (wid >> 1) * 64;
    const int wn   = (wid & 1) * 64;
    const int lrow  = lane & 15;
    const int khalf = lane >> 4;

    // stage one 128x32 tile pair; linear LDS dest, inverse-swizzled source.
    // 4 global_load_lds per thread per call.
    auto stage = [&](short* dA, short* dB, int k0) {
#pragma unroll
        for (int j = 0; j < 2; ++j) {
            int L    = j * 256 + tid;        // linear LDS granule 0..511
            int pr   = L >> 3;               // LDS row (128B)
            int slot = L & 7;
            int g    = slot ^ (pr & 7);      // logical granule
            int row  = pr * 2 + (g >> 2);    // tile row 0..127
            int kg   = g & 3;                // 16B col-granule
            int wb   = (j * 256 + (tid & ~63)) * 16;   // wave-uniform base
            {
                int grow = bm + row; if (grow >= M) grow = M - 1;
                const short* src = A + (size_t)grow * K + k0 + kg * 8;
                __builtin_amdgcn_global_load_lds(
                    (__attribute__((address_space(1))) void*)src,
                    (__attribute__((address_space(3))) void*)((char*)dA + wb),
                    16, 0, 0);
            }
            {
                int grow = bn + row; if (grow >= N) grow = N - 1;
                const short* src = B + (size_t)grow * K + k0 + kg * 8;
                __builtin_amdgcn_global_load_lds(
                    (__attribute__((address_space(1))) void*)src,
                    (__attribute__((address_space(3))) void*)((char*)dB + wb),
                    16, 0, 0);
            }
        }
    };

    // swizzled fragment read: tile row `row`, k-granule `khalf`
    auto frag = [&](const short* h, int row) -> bf16x8 {
        int pr   = row >> 1;
        int g    = ((row & 1) << 2) | khalf;
        int slot = g ^ (pr & 7);
        return *(const bf16x8*)&h[pr * 64 + slot * 8];
    };

    f32x4 acc[4][4] = {};
    const int nt = K >> 5;

    // prologue: 2 tiles in flight
    stage(As[0], Bs[0], 0);
    stage(As[1], Bs[1], 32);

    for (int t = 0; t < nt; ++t) {
        const unsigned cur = (unsigned)t % 3u;
        if (t + 2 < nt) {
            const unsigned nxt = (unsigned)(t + 2) % 3u;
            stage(As[nxt], Bs[nxt], (t + 2) << 5);
            // in flight: tiles t, t+1, t+2 (4 loads each) -> drain to 8 = t landed
            asm volatile("s_waitcnt vmcnt(8)" ::: "memory");
        } else if (t + 1 < nt) {
            asm volatile("s_waitcnt vmcnt(4)" ::: "memory");
        } else {
            asm volatile("s_waitcnt vmcnt(0)" ::: "memory");
        }
        __builtin_amdgcn_s_barrier();                         // buf[cur] ready

        const short* as = As[cur];
        const short* bs = Bs[cur];
        bf16x8 af[4], bfr[4];
#pragma unroll
        for (int m = 0; m < 4; ++m) af[m] = frag(as, wm + m * 16 + lrow);
#pragma unroll
        for (int n = 0; n < 4; ++n) bfr[n] = frag(bs, wn + n * 16 + lrow);

        // drain ds_reads, then release buf[cur] for iter t+1's staging of t+3
        asm volatile("s_waitcnt lgkmcnt(0)" ::: "memory");
        __builtin_amdgcn_sched_barrier(0);
        __builtin_amdgcn_s_barrier();

        __builtin_amdgcn_s_setprio(1);
#pragma unroll
        for (int m = 0; m < 4; ++m)
#pragma unroll
            for (int n = 0; n < 4; ++n)
                acc[m][n] = __builtin_amdgcn_mfma_f32_16x16x32_bf16(
                    af[m], bfr[n], acc[m][n], 0, 0, 0);
        __builtin_amdgcn_s_setprio(0);
    }

    // epilogue: D mapping col=lane&15, row=(lane>>4)*4+r  [m89]
    const int crow0 = (lane >> 4) * 4;
    const int ccol  = lane & 15;
#pragma unroll
    for (int m = 0; m < 4; ++m) {
#pragma unroll
        for (int n = 0; n < 4; ++n) {
            int col = bn + wn + n * 16 + ccol;
#pragma unroll
            for (int r2 = 0; r2 < 4; ++r2) {
                int row = bm + wm + m * 16 + crow0 + r2;
                if (row < M) Cp[(size_t)row * N + col] = f2bf(acc[m][n][r2]);
            }
        }
    }
}

// ----------------------- CSR degree count (seg only) ------------------------
__global__ void count_edges2(const int* __restrict__ segL, const int* __restrict__ segR,
                             int* __restrict__ cnt, int E, int N) {
    int i = blockIdx.x * blockDim.x + threadIdx.x;
    int st = gridDim.x * blockDim.x;
    for (; i < E; i += st) {
        atomicAdd(&cnt[segL[i]], 1);
        atomicAdd(&cnt[N + segR[i]], 1);
    }
}

// ------------------------------- CSR scan ----------------------------------
__global__ void scan_blocks(const int* __restrict__ cnt, int* __restrict__ off,
                            int* __restrict__ bsum, int n) {
    __shared__ int ws[4];
    int tid = threadIdx.x, lane = tid & 63, wid = tid >> 6;
    int i = blockIdx.x * 256 + tid;
    int x = (i < n) ? cnt[i] : 0;
    int v = x;
#pragma unroll
    for (int d = 1; d < 64; d <<= 1) {
        int t = __shfl_up(v, d, 64);
        if (lane >= d) v += t;
    }
    if (lane == 63) ws[wid] = v;
    __syncthreads();
    int woff = 0;
    for (int w = 0; w < wid; ++w) woff += ws[w];
    v += woff;
    if (i < n) off[i + 1] = v;
    if (tid == 255) bsum[blockIdx.x] = v;
}

__global__ void scan_tops(int* __restrict__ bsum, int nb) {
    __shared__ int ws[4];
    int tid = threadIdx.x, lane = tid & 63, wid = tid >> 6;
    int x = (tid < nb) ? bsum[tid] : 0;
    int v = x;
#pragma unroll
    for (int d = 1; d < 64; d <<= 1) {
        int t = __shfl_up(v, d, 64);
        if (lane >= d) v += t;
    }
    if (lane == 63) ws[wid] = v;
    __syncthreads();
    int woff = 0;
    for (int w = 0; w < wid; ++w) woff += ws[w];
    v += woff;
    if (tid < nb) bsum[tid] = v - x;
}

__global__ void scan_apply(int* __restrict__ off, const int* __restrict__ bsum,
                           int* __restrict__ cnt, int n) {
    int i = blockIdx.x * 256 + threadIdx.x;
    if (i < n) {
        off[i + 1] += bsum[blockIdx.x];
        cnt[i] = 0;                      // becomes the fill cursor
    }
    if (i == 0) off[0] = 0;
}

// -------- per-edge weight + DIRECT pair fill (fused edge_dot + fill) --------
// 4 edges per wave; w = exp(dot/T) (unnormalized, |s|<~6 so exact in fp32).
// Lanes 0-3 write both CSR slots for their edge.
__global__ void edge_dot_fill(const short* __restrict__ proj,
                              const int* __restrict__ segL, const int* __restrict__ segR,
                              const int* __restrict__ off, int* __restrict__ cur,
                              float2* __restrict__ pairs, int E, int N) {
    int e0 = blockIdx.x * 16 + (threadIdx.x >> 6) * 4;
    if (e0 >= E) return;
    int lane = threadIdx.x & 63;

    float sum[4];
#pragma unroll
    for (int k = 0; k < 4; ++k) {
        int ek = e0 + k; if (ek >= E) ek = e0;
        const short* a = proj + (size_t)segL[ek] * 1024 + lane * 8;          // K_L
        const short* b = proj + (size_t)(N + segR[ek]) * 1024 + lane * 8;    // K_R
        s16x8 va = *(const s16x8*)a;
        s16x8 vb = *(const s16x8*)b;
        float s = 0.f;
#pragma unroll
        for (int j = 0; j < 8; ++j) s += bf2f(va[j]) * bf2f(vb[j]);
        sum[k] = s;
    }
#pragma unroll
    for (int o = 32; o > 0; o >>= 1) {
#pragma unroll
        for (int k = 0; k < 4; ++k) sum[k] += __shfl_xor(sum[k], o, 64);
    }
    if (lane < 4) {
        int ek = e0 + lane;
        if (ek < E) {
            float s = (lane == 0) ? sum[0] : (lane == 1) ? sum[1]
                    : (lane == 2) ? sum[2] : sum[3];
            float we = __expf(s * TEMP_INV);
            int sl = segL[ek], sr = segR[ek];
            int pl = off[sl] + atomicAdd(&cur[sl], 1);
            pairs[pl] = make_float2(we, __int_as_float(N + sr));  // L dest <- R src
            int pr = off[N + sr] + atomicAdd(&cur[N + sr], 1);
            pairs[pr] = make_float2(we, __int_as_float(sl));      // R dest <- L src
        }
    }
}

// --------- per-node weighted VW sum + normalize + bias + LeakyReLU ----------
__global__ void node_msg(const int* __restrict__ off,
                         const float2* __restrict__ pairs,
                         const short* __restrict__ proj,
                         const float* __restrict__ bo,
                         float* __restrict__ out, int NN2) {
    int n = blockIdx.x * 4 + (threadIdx.x >> 6);
    if (n >= NN2) return;
    int lane = threadIdx.x & 63;
    int beg = off[n], end = off[n + 1];
    const short* VW = proj + 512 + lane * 8;   // VW half, stride 1024

    float acc[8] = {};
    float z = 0.f;
    int i = beg;
    for (; i + 3 < end; i += 4) {
        float2 p0 = pairs[i], p1 = pairs[i + 1];
        float2 p2 = pairs[i + 2], p3 = pairs[i + 3];
        const s16x8 v0 = *(const s16x8*)(VW + (size_t)__float_as_int(p0.y) * 1024);
        const s16x8 v1 = *(const s16x8*)(VW + (size_t)__float_as_int(p1.y) * 1024);
        const s16x8 v2 = *(const s16x8*)(VW + (size_t)__float_as_int(p2.y) * 1024);
        const s16x8 v3 = *(const s16x8*)(VW + (size_t)__float_as_int(p3.y) * 1024);
        z += (p0.x + p1.x) + (p2.x + p3.x);
#pragma unroll
        for (int j = 0; j < 8; ++j) {
            acc[j] += p0.x * bf2f(v0[j]) + p1.x * bf2f(v1[j]);
            acc[j] += p2.x * bf2f(v2[j]) + p3.x * bf2f(v3[j]);
        }
    }
    for (; i < end; ++i) {
        float2 p = pairs[i];
        const s16x8 v = *(const s16x8*)(VW + (size_t)__float_as_int(p.y) * 1024);
        z += p.x;
#pragma unroll
        for (int j = 0; j < 8; ++j) acc[j] += p.x * bf2f(v[j]);
    }
    float inv = (z > 0.f) ? 1.f / z : 0.f;

    float4 bs0 = *(const float4*)&bo[lane * 8];
    float4 bs1 = *(const float4*)&bo[lane * 8 + 4];
    float bb[8] = {bs0.x, bs0.y, bs0.z, bs0.w, bs1.x, bs1.y, bs1.z, bs1.w};
    f32x4 h0, h1;
#pragma unroll
    for (int j = 0; j < 4; ++j) {
        float v = acc[j] * inv + bb[j];
        h0[j] = v >= 0.f ? v : 0.01f * v;   // LeakyReLU
    }
#pragma unroll
    for (int j = 0; j < 4; ++j) {
        float v = acc[4 + j] * inv + bb[4 + j];
        h1[j] = v >= 0.f ? v : 0.01f * v;
    }
    float* orow = out + (size_t)n * C_DIM + lane * 8;
    __builtin_nontemporal_store(h0, (f32x4*)&orow[0]);
    __builtin_nontemporal_store(h1, (f32x4*)&orow[4]);
}

// ------------------------------- launcher ----------------------------------
extern "C" void kernel_launch(void* const* d_in, const int* in_sizes, int n_in,
                              void* d_out, int out_size, void* d_ws, size_t ws_size,
                              hipStream_t stream) {
    const float* node_left  = (const float*)d_in[0];
    const int*   segL       = (const int*)d_in[1];
    const float* node_right = (const float*)d_in[3];
    const int*   segR       = (const int*)d_in[4];
    const float* Wk         = (const float*)d_in[6];
    const float* Wv         = (const float*)d_in[7];
    const float* Wo         = (const float*)d_in[8];
    const float* bo         = (const float*)d_in[9];

    const int C = C_DIM;
    const int N = in_sizes[0] / C;   // 20000
    const int E = in_sizes[1];       // 160000
    const int NN2 = 2 * N;

    size_t offb = 0;
    auto alloc = [&](size_t bytes) -> void* {
        void* p = (char*)d_ws + offb;
        offb += (bytes + 255) & ~(size_t)255;
        return p;
    };
    short* nodeLR_b = (short*)alloc((size_t)NN2 * C * 2);     // [2N][512]
    short* Wkc_b  = (short*)alloc((size_t)1024 * C * 2);      // [Wk; Wc]
    short* Wc_b   = Wkc_b + (size_t)C * C;                    // rows 512-1023
    short* Wo_b   = (short*)alloc((size_t)C * C * 2);
    short* WvT_b  = (short*)alloc((size_t)C * C * 2);
    short* proj   = (short*)alloc((size_t)NN2 * 1024 * 2);    // [2N][1024] = [K|VW]
    float2* pairs = (float2*)alloc((size_t)2 * E * 8);
    int* cnt  = (int*)alloc((size_t)NN2 * 4);                 // degree, then cursor
    int* off  = (int*)alloc((size_t)(NN2 + 1) * 4);
    int* bsum = (int*)alloc(256 * 4);

    const int nsb = (NN2 + 255) / 256;

    // 1. CSR degrees + scan FIRST (depends only on seg arrays), then converts
    hipMemsetAsync(cnt, 0, (size_t)NN2 * 4, stream);
    count_edges2<<<512, 256, 0, stream>>>(segL, segR, cnt, E, N);
    scan_blocks<<<nsb, 256, 0, stream>>>(cnt, off, bsum, NN2);
    scan_tops<<<1, 256, 0, stream>>>(bsum, nsb);
    scan_apply<<<nsb, 256, 0, stream>>>(off, bsum, cnt, NN2);   // cnt -> cursor

    cvt2_f32_bf16<<<2048, 256, 0, stream>>>(node_left, node_right, nodeLR_b,
                                            (long)N * C / 4);
    cvt_weights<<<192, 256, 0, stream>>>(Wk, Wv, Wo, Wkc_b, Wo_b, WvT_b);

    // 2. Wc = Wo @ Wv;  proj = nodeLR @ [Wk; Wc]^T
    gemm_bt<<<16, 256, 0, stream>>>(Wo_b, WvT_b, Wc_b, C, C, C, 4, 16);
    {
        int nm = (NN2 + 127) / 128, nn = 1024 / 128;
        int total = nm * nn;
        gemm_bt<<<total, 256, 0, stream>>>(nodeLR_b, Wkc_b, proj, NN2, 1024, C,
                                           nn, total);
    }

    // 3. edge weights + direct pair fill (fused)
    edge_dot_fill<<<(E + 15) / 16, 256, 0, stream>>>(proj, segL, segR, off, cnt,
                                                     pairs, E, N);

    // 4. per-node weighted VW accumulate + bias + LeakyReLU -> d_out
    node_msg<<<(NN2 + 3) / 4, 256, 0, stream>>>(off, pairs, proj, bo,
                                                (float*)d_out, NN2);
}

// Round 10
// 211.590 us; speedup vs baseline: 1.1246x; 1.0876x over previous
//
#include <hip/hip_runtime.h>

// ---------------------------------------------------------------------------
// MultiHeadAttention graph-attention kernel for MI355X (gfx950).  Round 10.
// Algebraic cut: s[e] = xL·Wk^T · Wk·xR^T = xL · (G xR^T),  G = Wk^T Wk.
//   -> only right side needs K-projection (KR2 = nodeR @ G, G symmetric);
//      left K-operand is raw bf16 node_L.  Big-GEMM FLOPs x0.75.
// Output GEMM folded via Wc = Wo @ Wv (R5).  Both big GEMMs merged into ONE
// dual dispatch; both 512^3 weight GEMMs merged into one dual dispatch.
// GEMM core = R6's proven 2-buffer/counted-vmcnt/zero-conflict-swizzle 128^2.
// ---------------------------------------------------------------------------

#define C_DIM 512
#define TEMP_INV (1.0f / 22.627416997969522f)   // 1/sqrt(512)

using bf16x8 = __attribute__((ext_vector_type(8))) __bf16;
using s16x8  = __attribute__((ext_vector_type(8))) short;
using s16x4  = __attribute__((ext_vector_type(4))) short;
using f32x4  = __attribute__((ext_vector_type(4))) float;

__device__ __forceinline__ float bf2f(short u) {
    union { unsigned u; float f; } t;
    t.u = ((unsigned)(unsigned short)u) << 16;
    return t.f;
}
__device__ __forceinline__ short f2bf(float f) {
    union { float f; unsigned u; } t;
    t.f = f;
    unsigned r = t.u + 0x7FFFu + ((t.u >> 16) & 1u);  // RNE
    return (short)(r >> 16);
}

// ------------------- fp32 -> bf16 converts ---------------------------------
__global__ void cvt2_f32_bf16(const float* __restrict__ inA,
                              const float* __restrict__ inB,
                              short* __restrict__ out, long n4half) {
    long i = (long)blockIdx.x * blockDim.x + threadIdx.x;
    long stride = (long)gridDim.x * blockDim.x;
    long n4 = 2 * n4half;
    for (; i < n4; i += stride) {
        const float4* src = (i < n4half)
            ? reinterpret_cast<const float4*>(inA) + i
            : reinterpret_cast<const float4*>(inB) + (i - n4half);
        float4 v = *src;
        s16x4 o;
        o[0] = f2bf(v.x); o[1] = f2bf(v.y); o[2] = f2bf(v.z); o[3] = f2bf(v.w);
        reinterpret_cast<s16x4*>(out)[i] = o;
    }
}

// blocks 0-63: Wv -> WvT (transpose);  64-127: Wk -> WkT (transpose);
// 128-191: Wo -> WoB (straight).
__global__ void cvt_weights(const float* __restrict__ Wk,
                            const float* __restrict__ Wv,
                            const float* __restrict__ Wo,
                            short* __restrict__ WkT, short* __restrict__ WvT,
                            short* __restrict__ WoB) {
    int b = blockIdx.x;
    int tid = threadIdx.x;
    if (b < 128) {
        const float* src = (b < 64) ? Wv : Wk;
        short* dst = (b < 64) ? WvT : WkT;
        int bb = b & 63;
        __shared__ float t[64][65];
        int bx = bb & 7, by = bb >> 3;
#pragma unroll
        for (int i = 0; i < 4; ++i) {
            int idx = i * 256 + tid;
            int row = idx >> 4, c4 = idx & 15;
            float4 v = *(const float4*)&src[(size_t)(by * 64 + row) * 512 + bx * 64 + c4 * 4];
            t[row][c4 * 4 + 0] = v.x; t[row][c4 * 4 + 1] = v.y;
            t[row][c4 * 4 + 2] = v.z; t[row][c4 * 4 + 3] = v.w;
        }
        __syncthreads();
#pragma unroll
        for (int i = 0; i < 4; ++i) {
            int idx = i * 256 + tid;
            int row = idx >> 4, g = idx & 15;
            s16x4 o;
            o[0] = f2bf(t[g * 4 + 0][row]);
            o[1] = f2bf(t[g * 4 + 1][row]);
            o[2] = f2bf(t[g * 4 + 2][row]);
            o[3] = f2bf(t[g * 4 + 3][row]);
            *(s16x4*)&dst[(size_t)(bx * 64 + row) * 512 + by * 64 + g * 4] = o;
        }
    } else {
        long base = (long)(b & 63) * 1024;   // float4 units
#pragma unroll
        for (int i = 0; i < 4; ++i) {
            long idx = base + i * 256 + tid;
            float4 v = reinterpret_cast<const float4*>(Wo)[idx];
            s16x4 o;
            o[0] = f2bf(v.x); o[1] = f2bf(v.y); o[2] = f2bf(v.z); o[3] = f2bf(v.w);
            reinterpret_cast<s16x4*>(WoB)[idx] = o;
        }
    }
}

// ---------------------------- dual bf16 GEMM --------------------------------
// Two independent GEMMs C = A @ B^T (K = Ncols = 512) in one dispatch:
// swizzled block id < t0 -> GEMM0 (A0,B0,C0,M0), else GEMM1.
// Core: 128x128 tile, BK=32, 4 waves, 2-phase dbuf, counted vmcnt,
// paired-row zero-conflict LDS swizzle, bijective XCD block swizzle.
__global__ __launch_bounds__(256, 4)
void gemm_dual(const short* __restrict__ A0, const short* __restrict__ B0,
               short* __restrict__ C0, int M0, int t0,
               const short* __restrict__ A1, const short* __restrict__ B1,
               short* __restrict__ C1, int M1, int total) {
    __shared__ short As[2][128 * 32];
    __shared__ short Bs[2][128 * 32];

    // bijective XCD-chunked block swizzle (m204)
    const int bid = blockIdx.x;
    const int q = total >> 3, r = total & 7;
    const int xcd = bid & 7, idx = bid >> 3;
    const int swz = (xcd < r ? xcd * (q + 1) : r * (q + 1) + (xcd - r) * q) + idx;

    const short* A; const short* B; short* Cp; int M; int tile;
    if (swz < t0) { A = A0; B = B0; Cp = C0; M = M0; tile = swz; }
    else          { A = A1; B = B1; Cp = C1; M = M1; tile = swz - t0; }
    const int bm = (tile >> 2) * 128;      // nn = 512/128 = 4
    const int bn = (tile & 3) * 128;
    const int K = C_DIM;

    const int tid  = threadIdx.x;
    const int lane = tid & 63;
    const int wid  = tid >> 6;
    const int wm   = (wid >> 1) * 64;
    const int wn   = (wid & 1) * 64;
    const int lrow  = lane & 15;
    const int khalf = lane >> 4;

    // stage one 128x32 tile pair; linear LDS dest, inverse-swizzled source
    auto stage = [&](short* dA, short* dB, int k0) {
#pragma unroll
        for (int j = 0; j < 2; ++j) {
            int L    = j * 256 + tid;        // linear LDS granule 0..511
            int pr   = L >> 3;               // LDS row (128B)
            int slot = L & 7;
            int g    = slot ^ (pr & 7);      // logical granule
            int row  = pr * 2 + (g >> 2);    // tile row 0..127
            int kg   = g & 3;                // 16B col-granule
            int wb   = (j * 256 + (tid & ~63)) * 16;   // wave-uniform base
            {
                int grow = bm + row; if (grow >= M) grow = M - 1;
                const short* src = A + (size_t)grow * K + k0 + kg * 8;
                __builtin_amdgcn_global_load_lds(
                    (__attribute__((address_space(1))) void*)src,
                    (__attribute__((address_space(3))) void*)((char*)dA + wb),
                    16, 0, 0);
            }
            {
                int grow = bn + row;   // N = 512, always in range
                const short* src = B + (size_t)grow * K + k0 + kg * 8;
                __builtin_amdgcn_global_load_lds(
                    (__attribute__((address_space(1))) void*)src,
                    (__attribute__((address_space(3))) void*)((char*)dB + wb),
                    16, 0, 0);
            }
        }
    };

    // swizzled fragment read: tile row `row`, k-granule `khalf`
    auto frag = [&](const short* h, int row) -> bf16x8 {
        int pr   = row >> 1;
        int g    = ((row & 1) << 2) | khalf;
        int slot = g ^ (pr & 7);
        return *(const bf16x8*)&h[pr * 64 + slot * 8];
    };

    f32x4 acc[4][4] = {};
    const int nt = K >> 5;   // 16

    stage(As[0], Bs[0], 0);

    for (int t = 0; t < nt; ++t) {
        const int cur = t & 1;
        if (t + 1 < nt) {
            stage(As[cur ^ 1], Bs[cur ^ 1], (t + 1) << 5);
            asm volatile("s_waitcnt vmcnt(4)" ::: "memory");  // tile t landed
        } else {
            asm volatile("s_waitcnt vmcnt(0)" ::: "memory");
        }
        __builtin_amdgcn_s_barrier();                         // buf[cur] ready

        const short* as = As[cur];
        const short* bs = Bs[cur];
        bf16x8 af[4], bfr[4];
#pragma unroll
        for (int m = 0; m < 4; ++m) af[m] = frag(as, wm + m * 16 + lrow);
#pragma unroll
        for (int n = 0; n < 4; ++n) bfr[n] = frag(bs, wn + n * 16 + lrow);

        // drain ds_reads, then release buf[cur] for next iter's staging
        asm volatile("s_waitcnt lgkmcnt(0)" ::: "memory");
        __builtin_amdgcn_sched_barrier(0);
        __builtin_amdgcn_s_barrier();

        __builtin_amdgcn_s_setprio(1);
#pragma unroll
        for (int m = 0; m < 4; ++m)
#pragma unroll
            for (int n = 0; n < 4; ++n)
                acc[m][n] = __builtin_amdgcn_mfma_f32_16x16x32_bf16(
                    af[m], bfr[n], acc[m][n], 0, 0, 0);
        __builtin_amdgcn_s_setprio(0);
    }

    // epilogue: D mapping col=lane&15, row=(lane>>4)*4+r  [m89]
    const int crow0 = (lane >> 4) * 4;
    const int ccol  = lane & 15;
#pragma unroll
    for (int m = 0; m < 4; ++m) {
#pragma unroll
        for (int n = 0; n < 4; ++n) {
            int col = bn + wn + n * 16 + ccol;
#pragma unroll
            for (int r2 = 0; r2 < 4; ++r2) {
                int row = bm + wm + m * 16 + crow0 + r2;
                if (row < M) Cp[(size_t)row * C_DIM + col] = f2bf(acc[m][n][r2]);
            }
        }
    }
}

// ----------------------- CSR degree count (seg only) ------------------------
__global__ void count_edges2(const int* __restrict__ segL, const int* __restrict__ segR,
                             int* __restrict__ cnt, int E, int N) {
    int i = blockIdx.x * blockDim.x + threadIdx.x;
    int st = gridDim.x * blockDim.x;
    for (; i < E; i += st) {
        atomicAdd(&cnt[segL[i]], 1);
        atomicAdd(&cnt[N + segR[i]], 1);
    }
}

// ------------------------------- CSR scan ----------------------------------
__global__ void scan_blocks(const int* __restrict__ cnt, int* __restrict__ off,
                            int* __restrict__ bsum, int n) {
    __shared__ int ws[4];
    int tid = threadIdx.x, lane = tid & 63, wid = tid >> 6;
    int i = blockIdx.x * 256 + tid;
    int x = (i < n) ? cnt[i] : 0;
    int v = x;
#pragma unroll
    for (int d = 1; d < 64; d <<= 1) {
        int t = __shfl_up(v, d, 64);
        if (lane >= d) v += t;
    }
    if (lane == 63) ws[wid] = v;
    __syncthreads();
    int woff = 0;
    for (int w = 0; w < wid; ++w) woff += ws[w];
    v += woff;
    if (i < n) off[i + 1] = v;
    if (tid == 255) bsum[blockIdx.x] = v;
}

__global__ void scan_tops(int* __restrict__ bsum, int nb) {
    __shared__ int ws[4];
    int tid = threadIdx.x, lane = tid & 63, wid = tid >> 6;
    int x = (tid < nb) ? bsum[tid] : 0;
    int v = x;
#pragma unroll
    for (int d = 1; d < 64; d <<= 1) {
        int t = __shfl_up(v, d, 64);
        if (lane >= d) v += t;
    }
    if (lane == 63) ws[wid] = v;
    __syncthreads();
    int woff = 0;
    for (int w = 0; w < wid; ++w) woff += ws[w];
    v += woff;
    if (tid < nb) bsum[tid] = v - x;
}

__global__ void scan_apply(int* __restrict__ off, const int* __restrict__ bsum,
                           int* __restrict__ cnt, int n) {
    int i = blockIdx.x * 256 + threadIdx.x;
    if (i < n) {
        off[i + 1] += bsum[blockIdx.x];
        cnt[i] = 0;                      // becomes the fill cursor
    }
    if (i == 0) off[0] = 0;
}

// -------- per-edge weight + DIRECT pair fill (fused edge_dot + fill) --------
// s[e] = dot(nodeL_bf16[segL[e]], KR2[segR[e]]);  w = exp(s/T) unnormalized.
// Both operand arrays are [*][512] contiguous.  Lanes 0-3 write CSR slots.
__global__ void edge_dot_fill(const short* __restrict__ KL,   // nodeL bf16 [N][512]
                              const short* __restrict__ KR,   // KR2 [N][512]
                              const int* __restrict__ segL, const int* __restrict__ segR,
                              const int* __restrict__ off, int* __restrict__ cur,
                              float2* __restrict__ pairs, int E, int N) {
    int e0 = blockIdx.x * 16 + (threadIdx.x >> 6) * 4;
    if (e0 >= E) return;
    int lane = threadIdx.x & 63;

    float sum[4];
#pragma unroll
    for (int k = 0; k < 4; ++k) {
        int ek = e0 + k; if (ek >= E) ek = e0;
        const short* a = KL + (size_t)segL[ek] * 512 + lane * 8;
        const short* b = KR + (size_t)segR[ek] * 512 + lane * 8;
        s16x8 va = *(const s16x8*)a;
        s16x8 vb = *(const s16x8*)b;
        float s = 0.f;
#pragma unroll
        for (int j = 0; j < 8; ++j) s += bf2f(va[j]) * bf2f(vb[j]);
        sum[k] = s;
    }
#pragma unroll
    for (int o = 32; o > 0; o >>= 1) {
#pragma unroll
        for (int k = 0; k < 4; ++k) sum[k] += __shfl_xor(sum[k], o, 64);
    }
    if (lane < 4) {
        int ek = e0 + lane;
        if (ek < E) {
            float s = (lane == 0) ? sum[0] : (lane == 1) ? sum[1]
                    : (lane == 2) ? sum[2] : sum[3];
            float we = __expf(s * TEMP_INV);
            int sl = segL[ek], sr = segR[ek];
            int pl = off[sl] + atomicAdd(&cur[sl], 1);
            pairs[pl] = make_float2(we, __int_as_float(N + sr));  // L dest <- R src
            int pr = off[N + sr] + atomicAdd(&cur[N + sr], 1);
            pairs[pr] = make_float2(we, __int_as_float(sl));      // R dest <- L src
        }
    }
}

// --------- per-node weighted VW sum + normalize + bias + LeakyReLU ----------
// VW is [2N][512] bf16; pairs give (w, src_row).  Writes fp32 d_out.
__global__ void node_msg(const int* __restrict__ off,
                         const float2* __restrict__ pairs,
                         const short* __restrict__ VW,
                         const float* __restrict__ bo,
                         float* __restrict__ out, int NN2) {
    int n = blockIdx.x * 4 + (threadIdx.x >> 6);
    if (n >= NN2) return;
    int lane = threadIdx.x & 63;
    int beg = off[n], end = off[n + 1];
    const short* VWp = VW + lane * 8;

    float acc[8] = {};
    float z = 0.f;
    int i = beg;
    for (; i + 3 < end; i += 4) {
        float2 p0 = pairs[i], p1 = pairs[i + 1];
        float2 p2 = pairs[i + 2], p3 = pairs[i + 3];
        const s16x8 v0 = *(const s16x8*)(VWp + (size_t)__float_as_int(p0.y) * 512);
        const s16x8 v1 = *(const s16x8*)(VWp + (size_t)__float_as_int(p1.y) * 512);
        const s16x8 v2 = *(const s16x8*)(VWp + (size_t)__float_as_int(p2.y) * 512);
        const s16x8 v3 = *(const s16x8*)(VWp + (size_t)__float_as_int(p3.y) * 512);
        z += (p0.x + p1.x) + (p2.x + p3.x);
#pragma unroll
        for (int j = 0; j < 8; ++j) {
            acc[j] += p0.x * bf2f(v0[j]) + p1.x * bf2f(v1[j]);
            acc[j] += p2.x * bf2f(v2[j]) + p3.x * bf2f(v3[j]);
        }
    }
    for (; i < end; ++i) {
        float2 p = pairs[i];
        const s16x8 v = *(const s16x8*)(VWp + (size_t)__float_as_int(p.y) * 512);
        z += p.x;
#pragma unroll
        for (int j = 0; j < 8; ++j) acc[j] += p.x * bf2f(v[j]);
    }
    float inv = (z > 0.f) ? 1.f / z : 0.f;

    float4 bs0 = *(const float4*)&bo[lane * 8];
    float4 bs1 = *(const float4*)&bo[lane * 8 + 4];
    float bb[8] = {bs0.x, bs0.y, bs0.z, bs0.w, bs1.x, bs1.y, bs1.z, bs1.w};
    f32x4 h0, h1;
#pragma unroll
    for (int j = 0; j < 4; ++j) {
        float v = acc[j] * inv + bb[j];
        h0[j] = v >= 0.f ? v : 0.01f * v;   // LeakyReLU
    }
#pragma unroll
    for (int j = 0; j < 4; ++j) {
        float v = acc[4 + j] * inv + bb[4 + j];
        h1[j] = v >= 0.f ? v : 0.01f * v;
    }
    float* orow = out + (size_t)n * C_DIM + lane * 8;
    __builtin_nontemporal_store(h0, (f32x4*)&orow[0]);
    __builtin_nontemporal_store(h1, (f32x4*)&orow[4]);
}

// ------------------------------- launcher ----------------------------------
extern "C" void kernel_launch(void* const* d_in, const int* in_sizes, int n_in,
                              void* d_out, int out_size, void* d_ws, size_t ws_size,
                              hipStream_t stream) {
    const float* node_left  = (const float*)d_in[0];
    const int*   segL       = (const int*)d_in[1];
    const float* node_right = (const float*)d_in[3];
    const int*   segR       = (const int*)d_in[4];
    const float* Wk         = (const float*)d_in[6];
    const float* Wv         = (const float*)d_in[7];
    const float* Wo         = (const float*)d_in[8];
    const float* bo         = (const float*)d_in[9];

    const int C = C_DIM;
    const int N = in_sizes[0] / C;   // 20000
    const int E = in_sizes[1];       // 160000
    const int NN2 = 2 * N;

    size_t offb = 0;
    auto alloc = [&](size_t bytes) -> void* {
        void* p = (char*)d_ws + offb;
        offb += (bytes + 255) & ~(size_t)255;
        return p;
    };
    short* nodeLR_b = (short*)alloc((size_t)NN2 * C * 2);   // [2N][512] bf16 nodes
    short* nodeL_b  = nodeLR_b;
    short* nodeR_b  = nodeLR_b + (size_t)N * C;
    short* WkT_b = (short*)alloc((size_t)C * C * 2);
    short* WvT_b = (short*)alloc((size_t)C * C * 2);
    short* Wo_b  = (short*)alloc((size_t)C * C * 2);
    short* Wc_b  = (short*)alloc((size_t)C * C * 2);        // Wo @ Wv
    short* G_b   = (short*)alloc((size_t)C * C * 2);        // Wk^T @ Wk (symmetric)
    short* VW    = (short*)alloc((size_t)NN2 * C * 2);      // nodeLR @ Wc^T
    short* KR2   = (short*)alloc((size_t)N * C * 2);        // nodeR @ G
    float2* pairs = (float2*)alloc((size_t)2 * E * 8);
    int* cnt  = (int*)alloc((size_t)NN2 * 4);               // degree, then cursor
    int* off  = (int*)alloc((size_t)(NN2 + 1) * 4);
    int* bsum = (int*)alloc(256 * 4);

    const int nsb = (NN2 + 255) / 256;

    // 1. CSR degrees + scan (depends only on seg arrays)
    hipMemsetAsync(cnt, 0, (size_t)NN2 * 4, stream);
    count_edges2<<<512, 256, 0, stream>>>(segL, segR, cnt, E, N);
    scan_blocks<<<nsb, 256, 0, stream>>>(cnt, off, bsum, NN2);
    scan_tops<<<1, 256, 0, stream>>>(bsum, nsb);
    scan_apply<<<nsb, 256, 0, stream>>>(off, bsum, cnt, NN2);   // cnt -> cursor

    // 2. converts
    cvt2_f32_bf16<<<2048, 256, 0, stream>>>(node_left, node_right, nodeLR_b,
                                            (long)N * C / 4);
    cvt_weights<<<192, 256, 0, stream>>>(Wk, Wv, Wo, WkT_b, WvT_b, Wo_b);

    // 3. small dual GEMM: Wc = Wo @ Wv,  G = WkT @ WkT^T = Wk^T Wk
    gemm_dual<<<32, 256, 0, stream>>>(Wo_b, WvT_b, Wc_b, C, 16,
                                      WkT_b, WkT_b, G_b, C, 32);

    // 4. big dual GEMM: VW = nodeLR @ Wc^T (M=2N),  KR2 = nodeR @ G^T (M=N)
    {
        int t0 = ((NN2 + 127) / 128) * 4;
        int total = t0 + ((N + 127) / 128) * 4;
        gemm_dual<<<total, 256, 0, stream>>>(nodeLR_b, Wc_b, VW, NN2, t0,
                                             nodeR_b, G_b, KR2, N, total);
    }

    // 5. edge weights + direct pair fill (fused)
    edge_dot_fill<<<(E + 15) / 16, 256, 0, stream>>>(nodeL_b, KR2, segL, segR,
                                                     off, cnt, pairs, E, N);

    // 6. per-node weighted VW accumulate + bias + LeakyReLU -> d_out
    node_msg<<<(NN2 + 3) / 4, 256, 0, stream>>>(off, pairs, VW, bo,
                                                (float*)d_out, NN2);
}

// Round 12
// 201.294 us; speedup vs baseline: 1.1821x; 1.0512x over previous
//
#include <hip/hip_runtime.h>

// ---------------------------------------------------------------------------
// MultiHeadAttention graph-attention kernel for MI355X (gfx950).  Round 12.
// = R11 minus fp8 (accuracy fail: degree-1 nodes expose raw e4m3 error).
//   - G = Wk^T Wk score factoring (only right side projected for scores)
//   - Wc = Wo @ Wv output folding (no output GEMM)
//   - per-LEFT-node edge scores with register-resident K-row; lstL stores
//     segR so the gather chain stays 2-deep; left pair slots sequential.
//   - VW bf16 [2N][512]; node_msg = R10's proven version.
// GEMM core: R6 2-buffer / counted vmcnt / zero-conflict swizzle 128^2 dual.
// ---------------------------------------------------------------------------

#define C_DIM 512
#define TEMP_INV (1.0f / 22.627416997969522f)   // 1/sqrt(512)

using bf16x8 = __attribute__((ext_vector_type(8))) __bf16;
using s16x8  = __attribute__((ext_vector_type(8))) short;
using s16x4  = __attribute__((ext_vector_type(4))) short;
using f32x4  = __attribute__((ext_vector_type(4))) float;

__device__ __forceinline__ float bf2f(short u) {
    union { unsigned u; float f; } t;
    t.u = ((unsigned)(unsigned short)u) << 16;
    return t.f;
}
__device__ __forceinline__ short f2bf(float f) {
    union { float f; unsigned u; } t;
    t.f = f;
    unsigned r = t.u + 0x7FFFu + ((t.u >> 16) & 1u);  // RNE
    return (short)(r >> 16);
}

// ------------------- fp32 -> bf16 converts ---------------------------------
__global__ void cvt2_f32_bf16(const float* __restrict__ inA,
                              const float* __restrict__ inB,
                              short* __restrict__ out, long n4half) {
    long i = (long)blockIdx.x * blockDim.x + threadIdx.x;
    long stride = (long)gridDim.x * blockDim.x;
    long n4 = 2 * n4half;
    for (; i < n4; i += stride) {
        const float4* src = (i < n4half)
            ? reinterpret_cast<const float4*>(inA) + i
            : reinterpret_cast<const float4*>(inB) + (i - n4half);
        float4 v = *src;
        s16x4 o;
        o[0] = f2bf(v.x); o[1] = f2bf(v.y); o[2] = f2bf(v.z); o[3] = f2bf(v.w);
        reinterpret_cast<s16x4*>(out)[i] = o;
    }
}

// blocks 0-63: Wv -> WvT;  64-127: Wk -> WkT;  128-191: Wo -> WoB.
__global__ void cvt_weights(const float* __restrict__ Wk,
                            const float* __restrict__ Wv,
                            const float* __restrict__ Wo,
                            short* __restrict__ WkT, short* __restrict__ WvT,
                            short* __restrict__ WoB) {
    int b = blockIdx.x;
    int tid = threadIdx.x;
    if (b < 128) {
        const float* src = (b < 64) ? Wv : Wk;
        short* dst = (b < 64) ? WvT : WkT;
        int bb = b & 63;
        __shared__ float t[64][65];
        int bx = bb & 7, by = bb >> 3;
#pragma unroll
        for (int i = 0; i < 4; ++i) {
            int idx = i * 256 + tid;
            int row = idx >> 4, c4 = idx & 15;
            float4 v = *(const float4*)&src[(size_t)(by * 64 + row) * 512 + bx * 64 + c4 * 4];
            t[row][c4 * 4 + 0] = v.x; t[row][c4 * 4 + 1] = v.y;
            t[row][c4 * 4 + 2] = v.z; t[row][c4 * 4 + 3] = v.w;
        }
        __syncthreads();
#pragma unroll
        for (int i = 0; i < 4; ++i) {
            int idx = i * 256 + tid;
            int row = idx >> 4, g = idx & 15;
            s16x4 o;
            o[0] = f2bf(t[g * 4 + 0][row]);
            o[1] = f2bf(t[g * 4 + 1][row]);
            o[2] = f2bf(t[g * 4 + 2][row]);
            o[3] = f2bf(t[g * 4 + 3][row]);
            *(s16x4*)&dst[(size_t)(bx * 64 + row) * 512 + by * 64 + g * 4] = o;
        }
    } else {
        long base = (long)(b & 63) * 1024;   // float4 units
#pragma unroll
        for (int i = 0; i < 4; ++i) {
            long idx = base + i * 256 + tid;
            float4 v = reinterpret_cast<const float4*>(Wo)[idx];
            s16x4 o;
            o[0] = f2bf(v.x); o[1] = f2bf(v.y); o[2] = f2bf(v.z); o[3] = f2bf(v.w);
            reinterpret_cast<s16x4*>(WoB)[idx] = o;
        }
    }
}

// ---------------------------- dual bf16 GEMM --------------------------------
// Two GEMMs C = A @ B^T (N=K=512) in one dispatch; block < t0 -> GEMM0.
__global__ __launch_bounds__(256, 4)
void gemm_dual(const short* __restrict__ A0, const short* __restrict__ B0,
               short* __restrict__ C0, int M0, int t0,
               const short* __restrict__ A1, const short* __restrict__ B1,
               short* __restrict__ C1, int M1, int total) {
    __shared__ short As[2][128 * 32];
    __shared__ short Bs[2][128 * 32];

    // bijective XCD-chunked block swizzle (m204)
    const int bid = blockIdx.x;
    const int q = total >> 3, r = total & 7;
    const int xcd = bid & 7, idx = bid >> 3;
    const int swz = (xcd < r ? xcd * (q + 1) : r * (q + 1) + (xcd - r) * q) + idx;

    const short* A; const short* B; short* Cp; int M; int tile;
    if (swz < t0) { A = A0; B = B0; Cp = C0; M = M0; tile = swz; }
    else          { A = A1; B = B1; Cp = C1; M = M1; tile = swz - t0; }
    const int bm = (tile >> 2) * 128;      // nn = 512/128 = 4
    const int bn = (tile & 3) * 128;
    const int K = C_DIM;

    const int tid  = threadIdx.x;
    const int lane = tid & 63;
    const int wid  = tid >> 6;
    const int wm   = (wid >> 1) * 64;
    const int wn   = (wid & 1) * 64;
    const int lrow  = lane & 15;
    const int khalf = lane >> 4;

    auto stage = [&](short* dA, short* dB, int k0) {
#pragma unroll
        for (int j = 0; j < 2; ++j) {
            int L    = j * 256 + tid;        // linear LDS granule 0..511
            int pr   = L >> 3;               // LDS row (128B)
            int slot = L & 7;
            int g    = slot ^ (pr & 7);      // logical granule
            int row  = pr * 2 + (g >> 2);    // tile row 0..127
            int kg   = g & 3;                // 16B col-granule
            int wb   = (j * 256 + (tid & ~63)) * 16;   // wave-uniform base
            {
                int grow = bm + row; if (grow >= M) grow = M - 1;
                const short* src = A + (size_t)grow * K + k0 + kg * 8;
                __builtin_amdgcn_global_load_lds(
                    (__attribute__((address_space(1))) void*)src,
                    (__attribute__((address_space(3))) void*)((char*)dA + wb),
                    16, 0, 0);
            }
            {
                int grow = bn + row;   // N = 512, always in range
                const short* src = B + (size_t)grow * K + k0 + kg * 8;
                __builtin_amdgcn_global_load_lds(
                    (__attribute__((address_space(1))) void*)src,
                    (__attribute__((address_space(3))) void*)((char*)dB + wb),
                    16, 0, 0);
            }
        }
    };

    auto frag = [&](const short* h, int row) -> bf16x8 {
        int pr   = row >> 1;
        int g    = ((row & 1) << 2) | khalf;
        int slot = g ^ (pr & 7);
        return *(const bf16x8*)&h[pr * 64 + slot * 8];
    };

    f32x4 acc[4][4] = {};
    const int nt = K >> 5;   // 16

    stage(As[0], Bs[0], 0);

    for (int t = 0; t < nt; ++t) {
        const int cur = t & 1;
        if (t + 1 < nt) {
            stage(As[cur ^ 1], Bs[cur ^ 1], (t + 1) << 5);
            asm volatile("s_waitcnt vmcnt(4)" ::: "memory");  // tile t landed
        } else {
            asm volatile("s_waitcnt vmcnt(0)" ::: "memory");
        }
        __builtin_amdgcn_s_barrier();                         // buf[cur] ready

        const short* as = As[cur];
        const short* bs = Bs[cur];
        bf16x8 af[4], bfr[4];
#pragma unroll
        for (int m = 0; m < 4; ++m) af[m] = frag(as, wm + m * 16 + lrow);
#pragma unroll
        for (int n = 0; n < 4; ++n) bfr[n] = frag(bs, wn + n * 16 + lrow);

        asm volatile("s_waitcnt lgkmcnt(0)" ::: "memory");
        __builtin_amdgcn_sched_barrier(0);
        __builtin_amdgcn_s_barrier();

        __builtin_amdgcn_s_setprio(1);
#pragma unroll
        for (int m = 0; m < 4; ++m)
#pragma unroll
            for (int n = 0; n < 4; ++n)
                acc[m][n] = __builtin_amdgcn_mfma_f32_16x16x32_bf16(
                    af[m], bfr[n], acc[m][n], 0, 0, 0);
        __builtin_amdgcn_s_setprio(0);
    }

    // epilogue: D mapping col=lane&15, row=(lane>>4)*4+r  [m89]
    const int crow0 = (lane >> 4) * 4;
    const int ccol  = lane & 15;
#pragma unroll
    for (int m = 0; m < 4; ++m) {
#pragma unroll
        for (int n = 0; n < 4; ++n) {
            int col = bn + wn + n * 16 + ccol;
#pragma unroll
            for (int r2 = 0; r2 < 4; ++r2) {
                int row = bm + wm + m * 16 + crow0 + r2;
                if (row < M) Cp[(size_t)row * C_DIM + col] = f2bf(acc[m][n][r2]);
            }
        }
    }
}

// ----------------------- CSR degree count (seg only) ------------------------
__global__ void count_edges2(const int* __restrict__ segL, const int* __restrict__ segR,
                             int* __restrict__ cnt, int E, int N) {
    int i = blockIdx.x * blockDim.x + threadIdx.x;
    int st = gridDim.x * blockDim.x;
    for (; i < E; i += st) {
        atomicAdd(&cnt[segL[i]], 1);
        atomicAdd(&cnt[N + segR[i]], 1);
    }
}

// ------------------------------- CSR scan ----------------------------------
__global__ void scan_blocks(const int* __restrict__ cnt, int* __restrict__ off,
                            int* __restrict__ bsum, int n) {
    __shared__ int ws[4];
    int tid = threadIdx.x, lane = tid & 63, wid = tid >> 6;
    int i = blockIdx.x * 256 + tid;
    int x = (i < n) ? cnt[i] : 0;
    int v = x;
#pragma unroll
    for (int d = 1; d < 64; d <<= 1) {
        int t = __shfl_up(v, d, 64);
        if (lane >= d) v += t;
    }
    if (lane == 63) ws[wid] = v;
    __syncthreads();
    int woff = 0;
    for (int w = 0; w < wid; ++w) woff += ws[w];
    v += woff;
    if (i < n) off[i + 1] = v;
    if (tid == 255) bsum[blockIdx.x] = v;
}

__global__ void scan_tops(int* __restrict__ bsum, int nb) {
    __shared__ int ws[4];
    int tid = threadIdx.x, lane = tid & 63, wid = tid >> 6;
    int x = (tid < nb) ? bsum[tid] : 0;
    int v = x;
#pragma unroll
    for (int d = 1; d < 64; d <<= 1) {
        int t = __shfl_up(v, d, 64);
        if (lane >= d) v += t;
    }
    if (lane == 63) ws[wid] = v;
    __syncthreads();
    int woff = 0;
    for (int w = 0; w < wid; ++w) woff += ws[w];
    v += woff;
    if (tid < nb) bsum[tid] = v - x;
}

__global__ void scan_apply(int* __restrict__ off, const int* __restrict__ bsum,
                           int* __restrict__ cnt, int n) {
    int i = blockIdx.x * 256 + threadIdx.x;
    if (i < n) {
        off[i + 1] += bsum[blockIdx.x];
        cnt[i] = 0;                      // becomes the fill cursor
    }
    if (i == 0) off[0] = 0;
}

// -------- fill left edge lists: lstL[slot] = segR[e] (2-deep chain later) ---
__global__ void fill_lstL(const int* __restrict__ segL, const int* __restrict__ segR,
                          const int* __restrict__ off, int* __restrict__ curL,
                          int* __restrict__ lstL, int E) {
    int i = blockIdx.x * blockDim.x + threadIdx.x;
    int st = gridDim.x * blockDim.x;
    for (; i < E; i += st) {
        int sl = segL[i];
        int p = off[sl] + atomicAdd(&curL[sl], 1);
        lstL[p] = segR[i];
    }
}

// ------ per-LEFT-node edge scores + pair fill (K-row register-resident) -----
// One wave per left node.  KL row loaded once; per edge gather KR2 row, dot,
// exp; left pair slot sequential, right slot via atomic cursor.
__global__ void edge_left(const short* __restrict__ nodeL,
                          const short* __restrict__ KR2,
                          const int* __restrict__ lstL,
                          const int* __restrict__ off, int* __restrict__ curR,
                          float2* __restrict__ pairs, int N) {
    int n = blockIdx.x * 4 + (threadIdx.x >> 6);
    if (n >= N) return;
    int lane = threadIdx.x & 63;
    int beg = off[n], end = off[n + 1];
    if (beg == end) return;

    s16x8 kl = *(const s16x8*)(nodeL + (size_t)n * 512 + lane * 8);
    float klf[8];
#pragma unroll
    for (int j = 0; j < 8; ++j) klf[j] = bf2f(kl[j]);

    for (int k0 = beg; k0 < end; k0 += 4) {
        int sr0, sr1, sr2, sr3;
        float sum[4];
        {
            int k = k0;                       sr0 = lstL[k];
            k = (k0 + 1 < end) ? k0 + 1 : k0; sr1 = lstL[k];
            k = (k0 + 2 < end) ? k0 + 2 : k0; sr2 = lstL[k];
            k = (k0 + 3 < end) ? k0 + 3 : k0; sr3 = lstL[k];
        }
        const s16x8 kr0 = *(const s16x8*)(KR2 + (size_t)sr0 * 512 + lane * 8);
        const s16x8 kr1 = *(const s16x8*)(KR2 + (size_t)sr1 * 512 + lane * 8);
        const s16x8 kr2 = *(const s16x8*)(KR2 + (size_t)sr2 * 512 + lane * 8);
        const s16x8 kr3 = *(const s16x8*)(KR2 + (size_t)sr3 * 512 + lane * 8);
        float s0 = 0.f, s1 = 0.f, s2 = 0.f, s3 = 0.f;
#pragma unroll
        for (int j = 0; j < 8; ++j) {
            s0 += klf[j] * bf2f(kr0[j]);
            s1 += klf[j] * bf2f(kr1[j]);
            s2 += klf[j] * bf2f(kr2[j]);
            s3 += klf[j] * bf2f(kr3[j]);
        }
        sum[0] = s0; sum[1] = s1; sum[2] = s2; sum[3] = s3;
#pragma unroll
        for (int o = 32; o > 0; o >>= 1)
#pragma unroll
            for (int t = 0; t < 4; ++t) sum[t] += __shfl_xor(sum[t], o, 64);

        if (lane < 4 && k0 + lane < end) {
            float s  = (lane == 0) ? sum[0] : (lane == 1) ? sum[1]
                     : (lane == 2) ? sum[2] : sum[3];
            int  srx = (lane == 0) ? sr0 : (lane == 1) ? sr1
                     : (lane == 2) ? sr2 : sr3;
            float w = __expf(s * TEMP_INV);
            pairs[k0 + lane] = make_float2(w, __int_as_float(N + srx));  // L slot
            int pr = off[N + srx] + atomicAdd(&curR[N + srx], 1);
            pairs[pr] = make_float2(w, __int_as_float(n));               // R slot
        }
    }
}

// --------- per-node weighted VW sum + normalize + bias + LeakyReLU ----------
// VW is [2N][512] bf16; pairs give (w, src_row).  Writes fp32 d_out.
__global__ void node_msg(const int* __restrict__ off,
                         const float2* __restrict__ pairs,
                         const short* __restrict__ VW,
                         const float* __restrict__ bo,
                         float* __restrict__ out, int NN2) {
    int n = blockIdx.x * 4 + (threadIdx.x >> 6);
    if (n >= NN2) return;
    int lane = threadIdx.x & 63;
    int beg = off[n], end = off[n + 1];
    const short* VWp = VW + lane * 8;

    float acc[8] = {};
    float z = 0.f;
    int i = beg;
    for (; i + 3 < end; i += 4) {
        float2 p0 = pairs[i], p1 = pairs[i + 1];
        float2 p2 = pairs[i + 2], p3 = pairs[i + 3];
        const s16x8 v0 = *(const s16x8*)(VWp + (size_t)__float_as_int(p0.y) * 512);
        const s16x8 v1 = *(const s16x8*)(VWp + (size_t)__float_as_int(p1.y) * 512);
        const s16x8 v2 = *(const s16x8*)(VWp + (size_t)__float_as_int(p2.y) * 512);
        const s16x8 v3 = *(const s16x8*)(VWp + (size_t)__float_as_int(p3.y) * 512);
        z += (p0.x + p1.x) + (p2.x + p3.x);
#pragma unroll
        for (int j = 0; j < 8; ++j) {
            acc[j] += p0.x * bf2f(v0[j]) + p1.x * bf2f(v1[j]);
            acc[j] += p2.x * bf2f(v2[j]) + p3.x * bf2f(v3[j]);
        }
    }
    for (; i < end; ++i) {
        float2 p = pairs[i];
        const s16x8 v = *(const s16x8*)(VWp + (size_t)__float_as_int(p.y) * 512);
        z += p.x;
#pragma unroll
        for (int j = 0; j < 8; ++j) acc[j] += p.x * bf2f(v[j]);
    }
    float inv = (z > 0.f) ? 1.f / z : 0.f;

    float4 bs0 = *(const float4*)&bo[lane * 8];
    float4 bs1 = *(const float4*)&bo[lane * 8 + 4];
    float bb[8] = {bs0.x, bs0.y, bs0.z, bs0.w, bs1.x, bs1.y, bs1.z, bs1.w};
    f32x4 h0, h1;
#pragma unroll
    for (int j = 0; j < 4; ++j) {
        float v = acc[j] * inv + bb[j];
        h0[j] = v >= 0.f ? v : 0.01f * v;   // LeakyReLU
    }
#pragma unroll
    for (int j = 0; j < 4; ++j) {
        float v = acc[4 + j] * inv + bb[4 + j];
        h1[j] = v >= 0.f ? v : 0.01f * v;
    }
    float* orow = out + (size_t)n * C_DIM + lane * 8;
    __builtin_nontemporal_store(h0, (f32x4*)&orow[0]);
    __builtin_nontemporal_store(h1, (f32x4*)&orow[4]);
}

// ------------------------------- launcher ----------------------------------
extern "C" void kernel_launch(void* const* d_in, const int* in_sizes, int n_in,
                              void* d_out, int out_size, void* d_ws, size_t ws_size,
                              hipStream_t stream) {
    const float* node_left  = (const float*)d_in[0];
    const int*   segL       = (const int*)d_in[1];
    const float* node_right = (const float*)d_in[3];
    const int*   segR       = (const int*)d_in[4];
    const float* Wk         = (const float*)d_in[6];
    const float* Wv         = (const float*)d_in[7];
    const float* Wo         = (const float*)d_in[8];
    const float* bo         = (const float*)d_in[9];

    const int C = C_DIM;
    const int N = in_sizes[0] / C;   // 20000
    const int E = in_sizes[1];       // 160000
    const int NN2 = 2 * N;

    size_t offb = 0;
    auto alloc = [&](size_t bytes) -> void* {
        void* p = (char*)d_ws + offb;
        offb += (bytes + 255) & ~(size_t)255;
        return p;
    };
    short* nodeLR_b = (short*)alloc((size_t)NN2 * C * 2);   // [2N][512] bf16 nodes
    short* nodeL_b  = nodeLR_b;
    short* nodeR_b  = nodeLR_b + (size_t)N * C;
    short* WkT_b = (short*)alloc((size_t)C * C * 2);
    short* WvT_b = (short*)alloc((size_t)C * C * 2);
    short* Wo_b  = (short*)alloc((size_t)C * C * 2);
    short* Wc_b  = (short*)alloc((size_t)C * C * 2);        // Wo @ Wv
    short* G_b   = (short*)alloc((size_t)C * C * 2);        // Wk^T Wk
    short* VW    = (short*)alloc((size_t)NN2 * C * 2);      // nodeLR @ Wc^T, bf16
    short* KR2   = (short*)alloc((size_t)N * C * 2);        // nodeR @ G, bf16
    float2* pairs = (float2*)alloc((size_t)2 * E * 8);
    int* lstL = (int*)alloc((size_t)E * 4);
    int* cnt  = (int*)alloc((size_t)NN2 * 4);               // degree, then cursors
    int* off  = (int*)alloc((size_t)(NN2 + 1) * 4);
    int* bsum = (int*)alloc(256 * 4);

    const int nsb = (NN2 + 255) / 256;

    // 1. CSR degrees + scan (depends only on seg arrays), then left lists
    hipMemsetAsync(cnt, 0, (size_t)NN2 * 4, stream);
    count_edges2<<<512, 256, 0, stream>>>(segL, segR, cnt, E, N);
    scan_blocks<<<nsb, 256, 0, stream>>>(cnt, off, bsum, NN2);
    scan_tops<<<1, 256, 0, stream>>>(bsum, nsb);
    scan_apply<<<nsb, 256, 0, stream>>>(off, bsum, cnt, NN2);   // cnt -> cursors
    fill_lstL<<<512, 256, 0, stream>>>(segL, segR, off, cnt, lstL, E);

    // 2. converts
    cvt2_f32_bf16<<<2048, 256, 0, stream>>>(node_left, node_right, nodeLR_b,
                                            (long)N * C / 4);
    cvt_weights<<<192, 256, 0, stream>>>(Wk, Wv, Wo, WkT_b, WvT_b, Wo_b);

    // 3. small dual GEMM: Wc = Wo @ Wv,  G = Wk^T Wk
    gemm_dual<<<32, 256, 0, stream>>>(Wo_b, WvT_b, Wc_b, C, 16,
                                      WkT_b, WkT_b, G_b, C, 32);

    // 4. big dual GEMM: VW = nodeLR @ Wc^T (M=2N),  KR2 = nodeR @ G^T (M=N)
    {
        int t0 = ((NN2 + 127) / 128) * 4;
        int total = t0 + ((N + 127) / 128) * 4;
        gemm_dual<<<total, 256, 0, stream>>>(nodeLR_b, Wc_b, VW, NN2, t0,
                                             nodeR_b, G_b, KR2, N, total);
    }

    // 5. per-left-node edge scores + pair fill
    edge_left<<<(N + 3) / 4, 256, 0, stream>>>(nodeL_b, KR2, lstL, off, cnt,
                                               pairs, N);

    // 6. per-node weighted VW accumulate + bias + LeakyReLU -> d_out
    node_msg<<<(NN2 + 3) / 4, 256, 0, stream>>>(off, pairs, VW, bo,
                                                (float*)d_out, NN2);
}